// Round 8
// baseline (22121.432 us; speedup 1.0000x reference)
//
#include <hip/hip_runtime.h>
#include <hip/hip_bf16.h>
#include <math.h>

// 3-layer masked BiLSTM (B=32,T=1024,D=1024,H=512) + 4 heads.
// Round 8: self-flagging h exchange. Each h pair is a u64 [tag|h1|h0] stored
// fire-and-forget with relaxed agent atomics; consumers poll the DATA until
// tags match the step. No separate flags, no vmcnt drain, no fences:
// 4 fabric RTTs -> ~1 per step.

#define B_ 32
#define T_ 1024
#define H_ 512
#define NG 2048   // 4*H

typedef __attribute__((ext_vector_type(8))) short bf16x8;
typedef __attribute__((ext_vector_type(4))) float f32x4;
typedef unsigned int u32;
typedef unsigned long long u64;
typedef unsigned short u16;

__device__ inline u16 f2bf(float f) {          // round-to-nearest-even
    u32 u = __float_as_uint(f);
    return (u16)((u + 0x7fffu + ((u >> 16) & 1u)) >> 16);
}
__device__ inline float bf2f(u16 v) { return __uint_as_float(((u32)v) << 16); }
__device__ inline void gload16(const void* g, void* l) {
    __builtin_amdgcn_global_load_lds(
        (const __attribute__((address_space(1))) u32*)g,
        (__attribute__((address_space(3))) u32*)l, 16, 0, 0);
}
__device__ inline float fsig(float x) { return 1.0f / (1.0f + __expf(-x)); }
__device__ inline float ftanh(float x) { return 1.0f - 2.0f / (__expf(2.0f * x) + 1.0f); }

// ---------------------------------------------------------------- zero
__global__ void zero_mem(float* __restrict__ s, int n) {
    int i = blockIdx.x * 256 + threadIdx.x;
    if (i < n) s[i] = 0.0f;
}

// ---------------------------------------------------------------- fp32 -> bf16
__global__ __launch_bounds__(256) void conv_bf16(const float* __restrict__ src,
                                                 u16* __restrict__ dst) {
    int i = blockIdx.x * 256 + threadIdx.x;
    float4 v = *(const float4*)&src[(size_t)i * 4];
    ushort4 o = { f2bf(v.x), f2bf(v.y), f2bf(v.z), f2bf(v.w) };
    *(ushort4*)&dst[(size_t)i * 4] = o;
}

// ---------------------------------------------------------------- W transpose
// W [1024][2048] fp32  ->  wt [2048][1024] bf16   (6 matrices: l*2+dir)
__global__ __launch_bounds__(256) void transpose_w(const float* __restrict__ Wf,
                                                   const float* __restrict__ Wb,
                                                   u16* __restrict__ wt) {
    int mat = blockIdx.z;
    const float* W = ((mat & 1) ? Wb : Wf) + (size_t)(mat >> 1) * 1024 * NG;
    u16* dst = wt + (size_t)mat * NG * 1024;
    __shared__ float tile[64][65];
    int n0 = blockIdx.x * 64, k0 = blockIdx.y * 64;
    int t = threadIdx.x;
#pragma unroll
    for (int i = 0; i < 16; ++i) {
        int idx = t + i * 256;
        int kk = idx >> 6, nn = idx & 63;
        tile[kk][nn] = W[(size_t)(k0 + kk) * NG + n0 + nn];
    }
    __syncthreads();
#pragma unroll
    for (int i = 0; i < 16; ++i) {
        int idx = t + i * 256;
        int nn = idx >> 6, kk = idx & 63;
        dst[(size_t)(n0 + nn) * 1024 + k0 + kk] = f2bf(tile[kk][nn]);
    }
}

// ---------------------------------------------------------------- U pack
// U [512][2048] fp32 -> MFMA B-fragment order, bf16.
__global__ __launch_bounds__(256) void pack_u(const float* __restrict__ Uf,
                                              const float* __restrict__ Ub,
                                              u16* __restrict__ upk) {
    int mat = blockIdx.y;               // l*2 + dir
    const float* U = ((mat & 1) ? Ub : Uf) + (size_t)(mat >> 1) * H_ * NG;
    u16* dst = upk + (size_t)mat * 1048576;
    int f = blockIdx.x * 256 + threadIdx.x;
    int lane = f & 63, ks = (f >> 6) & 15, c2 = (f >> 10) & 1;
    int cp = (f >> 11) & 3, wg = f >> 13;
    int col = cp * H_ + wg * 32 + c2 * 16 + (lane & 15);
    int krow = ks * 32 + (lane >> 4) * 8;
    u16 o[8];
#pragma unroll
    for (int j = 0; j < 8; ++j) o[j] = f2bf(U[(size_t)(krow + j) * NG + col]);
    *(uint4*)(dst + (size_t)f * 8) = *(uint4*)o;
}

// ---------------------------------------------------------------- MFMA GEMM
// Zb[m][u*4+g] (bf16) = sum_k A[row(m)][k] * Bt[n=g*512+u][k] + bias[n]
__global__ __launch_bounds__(256) void gemm_mfma(
    const u16* __restrict__ A, const u16* __restrict__ Bt,
    const float* __restrict__ bias, u16* __restrict__ Zb,
    int t0, int lgC) {
    __shared__ __align__(16) u16 sA[128 * 32];
    __shared__ __align__(16) u16 sB[128 * 32];
    const int tid = threadIdx.x;
    const int m0 = blockIdx.y * 128, n0 = blockIdx.x * 128;
    const int Cmask = (1 << lgC) - 1;

    const int chunk0 = tid, chunk1 = tid + 256;
    const int r0 = chunk0 >> 2, kp0 = (chunk0 & 3) * 8;
    const int r1 = chunk1 >> 2, kp1 = (chunk1 & 3) * 8;
    const int gm0 = m0 + r0, gm1 = m0 + r1;
    const size_t arow0 = ((size_t)(gm0 >> lgC) * T_ + t0 + (gm0 & Cmask)) * 1024;
    const size_t arow1 = ((size_t)(gm1 >> lgC) * T_ + t0 + (gm1 & Cmask)) * 1024;
    const size_t brow0 = (size_t)(n0 + r0) * 1024;
    const size_t brow1 = (size_t)(n0 + r1) * 1024;

    const int lane = tid & 63, wave = tid >> 6;
    const int wr = (wave >> 1) * 64, wc = (wave & 1) * 64;
    const int fr = lane & 15, fk = (lane >> 4) * 8;

    f32x4 acc[4][4] = {};
    for (int kc = 0; kc < 1024; kc += 32) {
        gload16(A + arow0 + kc + kp0, &sA[chunk0 * 8]);
        gload16(A + arow1 + kc + kp1, &sA[chunk1 * 8]);
        gload16(Bt + brow0 + kc + kp0, &sB[chunk0 * 8]);
        gload16(Bt + brow1 + kc + kp1, &sB[chunk1 * 8]);
        __syncthreads();
        bf16x8 af[4], bfr[4];
#pragma unroll
        for (int i = 0; i < 4; ++i)
            af[i] = *(const bf16x8*)&sA[(wr + i * 16 + fr) * 32 + fk];
#pragma unroll
        for (int j = 0; j < 4; ++j)
            bfr[j] = *(const bf16x8*)&sB[(wc + j * 16 + fr) * 32 + fk];
#pragma unroll
        for (int i = 0; i < 4; ++i)
#pragma unroll
            for (int j = 0; j < 4; ++j)
                acc[i][j] = __builtin_amdgcn_mfma_f32_16x16x32_bf16(
                    af[i], bfr[j], acc[i][j], 0, 0, 0);
        __syncthreads();
    }
    float bv[4];
    int un[4], gn[4];
#pragma unroll
    for (int j = 0; j < 4; ++j) {
        int n = n0 + wc + j * 16 + fr;
        bv[j] = bias[n];
        un[j] = n & 511; gn[j] = n >> 9;
    }
#pragma unroll
    for (int i = 0; i < 4; ++i) {
        int mb = m0 + wr + i * 16 + (lane >> 4) * 4;
#pragma unroll
        for (int j = 0; j < 4; ++j) {
#pragma unroll
            for (int r = 0; r < 4; ++r)
                Zb[(size_t)(mb + r) * 2048 + un[j] * 4 + gn[j]] =
                    f2bf(acc[i][j][r] + bv[j]);
        }
    }
}

// ---------------------------------------------------------------- recurrence
// 32 wgs: dir = bx>>4, slice wgs = bx&15 owns u0 = wgs*32 (x4 gates).
// U bf16 fragments in registers. h exchange: u64 [tag|h1|h0] fire-and-forget
// agent atomic stores; consumers poll the data until tag==step. 2 buffers by
// step parity; tag makes overwrite-before-read impossible (producer's next
// poll blocks on the slowest wg).
__global__ __launch_bounds__(512, 1) void lstm_chunk(
    const u16* __restrict__ zf, const u16* __restrict__ zb,
    const u16* __restrict__ upk,          // layer base [2 dirs][1048576]
    const int* __restrict__ xmask,
    u64* __restrict__ hbuf64,             // [2 dir][2 parity][8192] u64
    float* __restrict__ cst, float* __restrict__ hst,  // [2*16384]
    u16* __restrict__ hseq,               // [B][T][1024] bf16
    int t0f, int t0b, int C, int sbase) {
    const int bx = blockIdx.x, dir = bx >> 4, wgs = bx & 15, u0 = wgs * 32;
    const u16* z = dir ? zb : zf;         // [B*C][2048] u16, idx u*4+g
    const u16* up = upk + dir * 1048576;
    u64* hb64 = hbuf64 + dir * 16384;
    const int tid = threadIdx.x;
    const int wave = tid >> 6, lane = tid & 63;
    const int cp = wave & 3, bt = wave >> 2, fr = lane & 15, fq = lane >> 4;
    const int row = bt * 16 + fr;                 // batch index for A frags
    const int swz = (row & 7) << 4;

    __shared__ __align__(16) u16 sh[16384];       // 32KB staged h (swizzled)
    __shared__ float sacc[32 * 132];              // gate preacts

    // U fragments -> registers (stationary across the chunk)
    bf16x8 uf0[16], uf1[16];
#pragma unroll
    for (int ks = 0; ks < 16; ++ks) {
        size_t base0 = (((size_t)(wgs * 4 + cp) * 2) * 16 + ks) * 512 + lane * 8;
        uf0[ks] = *(const bf16x8*)(up + base0);
        uf1[ks] = *(const bf16x8*)(up + base0 + 16 * 512);
    }

    const int b0p = tid >> 5, ul = tid & 31, b1p = b0p + 16, ug = u0 + ul;
    const int sidx = (dir * 16 + wgs) * 1024 + tid * 2;
    float c0r = cst[sidx], c1r = cst[sidx + 1];
    float h0r = hst[sidx], h1r = hst[sidx + 1];
    const size_t hs0 = (size_t)b0p * T_ * 1024 + dir * 512 + ug;
    const size_t hs1 = (size_t)b1p * T_ * 1024 + dir * 512 + ug;

    // prologue: poll+stage state(sbase) from buffer[sbase&1]
    {
        const u64* src = hb64 + ((sbase & 1) ? 8192 : 0);
        const u32 tg0 = (u32)sbase;
        u32 pend = 0xffffu;
        u64 got[16];
        do {
#pragma unroll
            for (int k = 0; k < 16; ++k) {
                if (pend & (1u << k)) {
                    u64 v = __hip_atomic_load(src + k * 512 + tid,
                                              __ATOMIC_RELAXED,
                                              __HIP_MEMORY_SCOPE_AGENT);
                    if ((u32)(v >> 32) == tg0) { got[k] = v; pend &= ~(1u << k); }
                }
            }
        } while (pend);
#pragma unroll
        for (int k = 0; k < 16; ++k) {
            int idx = k * 512 + tid;
            int sb = (idx * 4) ^ (((idx >> 8) & 7) << 4);
            *(u32*)((char*)sh + sb) = (u32)got[k];
        }
    }
    // z/mask for step 0
    ushort4 za0, za1; int mc0, mc1;
    {
        int tc = dir ? (C - 1) : 0;
        int t = dir ? (t0b + C - 1) : t0f;
        za0 = *(const ushort4*)(z + ((size_t)(b0p * C + tc)) * 2048 + ug * 4);
        za1 = *(const ushort4*)(z + ((size_t)(b1p * C + tc)) * 2048 + ug * 4);
        mc0 = xmask[b0p * T_ + t]; mc1 = xmask[b1p * T_ + t];
    }
    __syncthreads();

    for (int st = 0; st < C; ++st) {
        const int t = dir ? (t0b + C - 1 - st) : (t0f + st);
        const u32 tgt = (u32)(sbase + st + 1);
        u64* nx64 = hb64 + ((tgt & 1) ? 8192 : 0);

        // MFMA from LDS (swizzled) x register U, over K=512
        f32x4 acc0 = {0, 0, 0, 0}, acc1 = {0, 0, 0, 0};
#pragma unroll
        for (int ks = 0; ks < 16; ++ks) {
            int abyte = (row * 1024 + ks * 64 + fq * 16) ^ swz;
            bf16x8 a = *(const bf16x8*)((const char*)sh + abyte);
            acc0 = __builtin_amdgcn_mfma_f32_16x16x32_bf16(a, uf0[ks], acc0, 0, 0, 0);
            acc1 = __builtin_amdgcn_mfma_f32_16x16x32_bf16(a, uf1[ks], acc1, 0, 0, 0);
        }
#pragma unroll
        for (int j = 0; j < 4; ++j) {
            int b = bt * 16 + fq * 4 + j;
            sacc[b * 132 + cp * 32 + fr] = acc0[j];
            sacc[b * 132 + cp * 32 + 16 + fr] = acc1[j];
        }
        __syncthreads();   // sacc visible; all sh reads of this step done
        // pointwise gates + state update + tagged fire-and-forget h stores
        {
            const float* s0 = sacc + b0p * 132;
            const float* s1 = sacc + b1p * 132;
            float i0 = fsig(bf2f(za0.x) + s0[ul]);
            float f0 = fsig(bf2f(za0.y) + s0[32 + ul]);
            float g0 = ftanh(bf2f(za0.z) + s0[64 + ul]);
            float o0 = fsig(bf2f(za0.w) + s0[96 + ul]);
            if (mc0 != 1) { c0r = f0 * c0r + i0 * g0; h0r = o0 * ftanh(c0r); }
            float i1 = fsig(bf2f(za1.x) + s1[ul]);
            float f1 = fsig(bf2f(za1.y) + s1[32 + ul]);
            float g1 = ftanh(bf2f(za1.z) + s1[64 + ul]);
            float o1 = fsig(bf2f(za1.w) + s1[96 + ul]);
            if (mc1 != 1) { c1r = f1 * c1r + i1 * g1; h1r = o1 * ftanh(c1r); }
            u16 hb0s = f2bf(h0r), hb1s = f2bf(h1r);
            u32 nb0 = __shfl_xor((u32)hb0s, 1, 64);
            u32 nb1 = __shfl_xor((u32)hb1s, 1, 64);
            if ((ul & 1) == 0) {
                u64 w0 = ((u64)tgt << 32) | (u32)hb0s | (nb0 << 16);
                u64 w1 = ((u64)tgt << 32) | (u32)hb1s | (nb1 << 16);
                __hip_atomic_store(nx64 + b0p * 256 + (ug >> 1), w0,
                                   __ATOMIC_RELAXED, __HIP_MEMORY_SCOPE_AGENT);
                __hip_atomic_store(nx64 + b1p * 256 + (ug >> 1), w1,
                                   __ATOMIC_RELAXED, __HIP_MEMORY_SCOPE_AGENT);
            }
            hseq[hs0 + (size_t)t * 1024] = hb0s;
            hseq[hs1 + (size_t)t * 1024] = hb1s;
        }
        // prefetch next-step z/mask (independent, overlaps store latency)
        {
            int stn = (st + 1 < C) ? st + 1 : st;
            int tcn = dir ? (C - 1 - stn) : stn;
            int tn = dir ? (t0b + tcn) : (t0f + tcn);
            za0 = *(const ushort4*)(z + ((size_t)(b0p * C + tcn)) * 2048 + ug * 4);
            za1 = *(const ushort4*)(z + ((size_t)(b1p * C + tcn)) * 2048 + ug * 4);
            mc0 = xmask[b0p * T_ + tn]; mc1 = xmask[b1p * T_ + tn];
        }
        // poll+stage next state directly from the tagged data
        if (st + 1 < C) {
            const u64* src = nx64;
            u32 pend = 0xffffu;
            u64 got[16];
            do {
#pragma unroll
                for (int k = 0; k < 16; ++k) {
                    if (pend & (1u << k)) {
                        u64 v = __hip_atomic_load(src + k * 512 + tid,
                                                  __ATOMIC_RELAXED,
                                                  __HIP_MEMORY_SCOPE_AGENT);
                        if ((u32)(v >> 32) == tgt) { got[k] = v; pend &= ~(1u << k); }
                    }
                }
            } while (pend);
#pragma unroll
            for (int k = 0; k < 16; ++k) {
                int idx = k * 512 + tid;
                int sb = (idx * 4) ^ (((idx >> 8) & 7) << 4);
                *(u32*)((char*)sh + sb) = (u32)got[k];
            }
        }
        __syncthreads();   // sh staged by all; sacc reads done before rewrite
    }
    cst[sidx] = c0r; cst[sidx + 1] = c1r;
    hst[sidx] = h0r; hst[sidx + 1] = h1r;
}

// ---------------------------------------------------------------- heads
__global__ __launch_bounds__(256) void heads_kernel(
    const u16* __restrict__ xin,
    const float* __restrict__ Wp, const float* __restrict__ bp,
    const float* __restrict__ Wbu, const float* __restrict__ bbu,
    const float* __restrict__ Wss3, const float* __restrict__ bss3,
    const float* __restrict__ Wss8, const float* __restrict__ bss8,
    float* __restrict__ out) {
    const int r = blockIdx.x * 4 + (threadIdx.x >> 6);
    const int lane = threadIdx.x & 63;
    const u16* xr = xin + (size_t)r * 1024 + lane * 16;
    uint4 q0 = *(const uint4*)xr;
    uint4 q1 = *(const uint4*)(xr + 8);
    float xv[16];
    u32 qs[8] = { q0.x, q0.y, q0.z, q0.w, q1.x, q1.y, q1.z, q1.w };
#pragma unroll
    for (int i = 0; i < 8; ++i) {
        xv[i * 2]     = fmaxf(__uint_as_float((qs[i] & 0xffffu) << 16), 0.0f);
        xv[i * 2 + 1] = fmaxf(__uint_as_float(qs[i] & 0xffff0000u), 0.0f);
    }
    float acc[15] = {};
    const int k0 = lane * 16;
#pragma unroll
    for (int kk = 0; kk < 16; kk++) {
        float xk = xv[kk];
        int k = k0 + kk;
        acc[0] += xk * Wp[k * 2];      acc[1] += xk * Wp[k * 2 + 1];
        acc[2] += xk * Wbu[k * 2];     acc[3] += xk * Wbu[k * 2 + 1];
        acc[4] += xk * Wss3[k * 3];    acc[5] += xk * Wss3[k * 3 + 1];
        acc[6] += xk * Wss3[k * 3 + 2];
#pragma unroll
        for (int o = 0; o < 8; o++) acc[7 + o] += xk * Wss8[k * 8 + o];
    }
#pragma unroll
    for (int o = 0; o < 15; o++) {
#pragma unroll
        for (int off = 32; off; off >>= 1) acc[o] += __shfl_xor(acc[o], off, 64);
    }
    if (lane == 0) {
        float a0 = acc[0] + bp[0], a1 = acc[1] + bp[1];
        float mx = fmaxf(a0, a1);
        float e0 = expf(a0 - mx), e1 = expf(a1 - mx);
        float ssum = e0 + e1;
        out[(size_t)r * 2] = e0 / ssum;
        out[(size_t)r * 2 + 1] = e1 / ssum;
        float* ob = out + 65536;
        ob[r * 2] = acc[2] + bbu[0]; ob[r * 2 + 1] = acc[3] + bbu[1];
        float* o3 = out + 131072;
        o3[r * 3 + 0] = acc[4] + bss3[0];
        o3[r * 3 + 1] = acc[5] + bss3[1];
        o3[r * 3 + 2] = acc[6] + bss3[2];
        float* o8 = out + 229376;
#pragma unroll
        for (int o = 0; o < 8; o++) o8[r * 8 + o] = acc[7 + o] + bss8[o];
    }
}

// ---------------------------------------------------------------- launch
extern "C" void kernel_launch(void* const* d_in, const int* in_sizes, int n_in,
                              void* d_out, int out_size, void* d_ws, size_t ws_size,
                              hipStream_t stream) {
    const float* x = (const float*)d_in[0];
    const int* xmask = (const int*)d_in[1];
    const float* Wf = (const float*)d_in[2];
    const float* Uf = (const float*)d_in[3];
    const float* bfp = (const float*)d_in[4];
    const float* Wb = (const float*)d_in[5];
    const float* Ub = (const float*)d_in[6];
    const float* bbp = (const float*)d_in[7];
    const float* Wp = (const float*)d_in[8];
    const float* bp = (const float*)d_in[9];
    const float* Wbu = (const float*)d_in[10];
    const float* bbu = (const float*)d_in[11];
    const float* Wss3 = (const float*)d_in[12];
    const float* bss3 = (const float*)d_in[13];
    const float* Wss8 = (const float*)d_in[14];
    const float* bss8 = (const float*)d_in[15];

    char* wsb = (char*)d_ws;
    u16* actA = (u16*)wsb;                               // 64 MB
    u16* actB = (u16*)(wsb + (64ull << 20));             // 64 MB
    u16* wt   = (u16*)(wsb + (128ull << 20));            // 24 MB
    u16* upk  = (u16*)(wsb + (152ull << 20));            // 12 MB
    char* stb = wsb + (164ull << 20);                    // states
    u64* hbuf64 = (u64*)stb;                             // 262144 B
    float* cst = (float*)(stb + 262144);                 // 131072 B
    float* hst = (float*)(stb + 393216);                 // 131072 B
    const int stateFloats = 524288 / 4;

    size_t fixedB = 165ull << 20;
    int C = 1024;
    while (C > 128 && fixedB + 262144ull * C > ws_size) C >>= 1;
    int lgC = 31 - __builtin_clz((unsigned)C);
    u16* zf = (u16*)(wsb + fixedB);
    u16* zb = zf + (size_t)B_ * C * 2048;

    conv_bf16<<<dim3(8388608 / 256), 256, 0, stream>>>(x, actA);
    transpose_w<<<dim3(32, 16, 6), 256, 0, stream>>>(Wf, Wb, wt);
    pack_u<<<dim3(512, 6), 256, 0, stream>>>(Uf, Ub, upk);

    const u16* cur = actA;
    for (int l = 0; l < 3; l++) {
        u16* dst = (l & 1) ? actA : actB;
        zero_mem<<<dim3((stateFloats + 255) / 256), 256, 0, stream>>>(
            (float*)stb, stateFloats);
        u16* wtf = wt + (size_t)(l * 2 + 0) * NG * 1024;
        u16* wtb = wt + (size_t)(l * 2 + 1) * NG * 1024;
        const u16* upkl = upk + (size_t)l * 2 * 1048576;
        const float* bfl = bfp + l * NG;
        const float* bbl = bbp + l * NG;
        for (int c0 = 0; c0 < T_; c0 += C) {
            int t0f = c0;
            int t0b = T_ - c0 - C;
            dim3 ggrid(NG / 128, (B_ * C) / 128);
            gemm_mfma<<<ggrid, 256, 0, stream>>>(cur, wtf, bfl, zf, t0f, lgC);
            gemm_mfma<<<ggrid, 256, 0, stream>>>(cur, wtb, bbl, zb, t0b, lgC);

            const u16* a_zf = zf; const u16* a_zb = zb;
            const u16* a_up = upkl; const int* a_xm = xmask;
            u64* a_hb = hbuf64; float* a_cs = cst; float* a_hs = hst;
            u16* a_hseq = dst;
            int a_t0f = t0f, a_t0b = t0b, a_C = C, a_sb = c0;
            void* kargs[] = { &a_zf, &a_zb, &a_up, &a_xm, &a_hb, &a_cs, &a_hs,
                              &a_hseq, &a_t0f, &a_t0b, &a_C, &a_sb };
            hipLaunchCooperativeKernel((void*)lstm_chunk, dim3(32), dim3(512),
                                       kargs, 0, stream);
        }
        cur = dst;
    }
    heads_kernel<<<dim3(B_ * T_ / 4), 256, 0, stream>>>(
        cur, Wp, bp, Wbu, bbu, Wss3, bss3, Wss8, bss8, (float*)d_out);
}

// Round 9
// 11786.844 us; speedup vs baseline: 1.8768x; 1.8768x over previous
//
#include <hip/hip_runtime.h>
#include <hip/hip_bf16.h>
#include <math.h>

// 3-layer masked BiLSTM (B=32,T=1024,D=1024,H=512) + 4 heads.
// Round 9: r7 structure + chain trims: per-wave flag poll (no post-poll
// barrier), packed 64B flag line, hseq stores hidden under poll+gather,
// implicit barrier drains only (no redundant vmcnt asm).

#define B_ 32
#define T_ 1024
#define H_ 512
#define NG 2048   // 4*H

typedef __attribute__((ext_vector_type(8))) short bf16x8;
typedef __attribute__((ext_vector_type(4))) float f32x4;
typedef unsigned int u32;
typedef unsigned short u16;

__device__ inline u16 f2bf(float f) {          // round-to-nearest-even
    u32 u = __float_as_uint(f);
    return (u16)((u + 0x7fffu + ((u >> 16) & 1u)) >> 16);
}
__device__ inline float bf2f(u16 v) { return __uint_as_float(((u32)v) << 16); }
__device__ inline void gload16(const void* g, void* l) {
    __builtin_amdgcn_global_load_lds(
        (const __attribute__((address_space(1))) u32*)g,
        (__attribute__((address_space(3))) u32*)l, 16, 0, 0);
}
__device__ inline float fsig(float x) { return 1.0f / (1.0f + __expf(-x)); }
__device__ inline float ftanh(float x) { return 1.0f - 2.0f / (__expf(2.0f * x) + 1.0f); }

// ---------------------------------------------------------------- zero
__global__ void zero_mem(float* __restrict__ s, int n) {
    int i = blockIdx.x * 256 + threadIdx.x;
    if (i < n) s[i] = 0.0f;
}

// ---------------------------------------------------------------- fp32 -> bf16
__global__ __launch_bounds__(256) void conv_bf16(const float* __restrict__ src,
                                                 u16* __restrict__ dst) {
    int i = blockIdx.x * 256 + threadIdx.x;
    float4 v = *(const float4*)&src[(size_t)i * 4];
    ushort4 o = { f2bf(v.x), f2bf(v.y), f2bf(v.z), f2bf(v.w) };
    *(ushort4*)&dst[(size_t)i * 4] = o;
}

// ---------------------------------------------------------------- W transpose
// W [1024][2048] fp32  ->  wt [2048][1024] bf16   (6 matrices: l*2+dir)
__global__ __launch_bounds__(256) void transpose_w(const float* __restrict__ Wf,
                                                   const float* __restrict__ Wb,
                                                   u16* __restrict__ wt) {
    int mat = blockIdx.z;
    const float* W = ((mat & 1) ? Wb : Wf) + (size_t)(mat >> 1) * 1024 * NG;
    u16* dst = wt + (size_t)mat * NG * 1024;
    __shared__ float tile[64][65];
    int n0 = blockIdx.x * 64, k0 = blockIdx.y * 64;
    int t = threadIdx.x;
#pragma unroll
    for (int i = 0; i < 16; ++i) {
        int idx = t + i * 256;
        int kk = idx >> 6, nn = idx & 63;
        tile[kk][nn] = W[(size_t)(k0 + kk) * NG + n0 + nn];
    }
    __syncthreads();
#pragma unroll
    for (int i = 0; i < 16; ++i) {
        int idx = t + i * 256;
        int nn = idx >> 6, kk = idx & 63;
        dst[(size_t)(n0 + nn) * 1024 + k0 + kk] = f2bf(tile[kk][nn]);
    }
}

// ---------------------------------------------------------------- U pack
// U [512][2048] fp32 -> MFMA B-fragment order, bf16.
__global__ __launch_bounds__(256) void pack_u(const float* __restrict__ Uf,
                                              const float* __restrict__ Ub,
                                              u16* __restrict__ upk) {
    int mat = blockIdx.y;               // l*2 + dir
    const float* U = ((mat & 1) ? Ub : Uf) + (size_t)(mat >> 1) * H_ * NG;
    u16* dst = upk + (size_t)mat * 1048576;
    int f = blockIdx.x * 256 + threadIdx.x;
    int lane = f & 63, ks = (f >> 6) & 15, c2 = (f >> 10) & 1;
    int cp = (f >> 11) & 3, wg = f >> 13;
    int col = cp * H_ + wg * 32 + c2 * 16 + (lane & 15);
    int krow = ks * 32 + (lane >> 4) * 8;
    u16 o[8];
#pragma unroll
    for (int j = 0; j < 8; ++j) o[j] = f2bf(U[(size_t)(krow + j) * NG + col]);
    *(uint4*)(dst + (size_t)f * 8) = *(uint4*)o;
}

// ---------------------------------------------------------------- MFMA GEMM
// Zb[m][u*4+g] (bf16) = sum_k A[row(m)][k] * Bt[n=g*512+u][k] + bias[n]
__global__ __launch_bounds__(256) void gemm_mfma(
    const u16* __restrict__ A, const u16* __restrict__ Bt,
    const float* __restrict__ bias, u16* __restrict__ Zb,
    int t0, int lgC) {
    __shared__ __align__(16) u16 sA[128 * 32];
    __shared__ __align__(16) u16 sB[128 * 32];
    const int tid = threadIdx.x;
    const int m0 = blockIdx.y * 128, n0 = blockIdx.x * 128;
    const int Cmask = (1 << lgC) - 1;

    const int chunk0 = tid, chunk1 = tid + 256;
    const int r0 = chunk0 >> 2, kp0 = (chunk0 & 3) * 8;
    const int r1 = chunk1 >> 2, kp1 = (chunk1 & 3) * 8;
    const int gm0 = m0 + r0, gm1 = m0 + r1;
    const size_t arow0 = ((size_t)(gm0 >> lgC) * T_ + t0 + (gm0 & Cmask)) * 1024;
    const size_t arow1 = ((size_t)(gm1 >> lgC) * T_ + t0 + (gm1 & Cmask)) * 1024;
    const size_t brow0 = (size_t)(n0 + r0) * 1024;
    const size_t brow1 = (size_t)(n0 + r1) * 1024;

    const int lane = tid & 63, wave = tid >> 6;
    const int wr = (wave >> 1) * 64, wc = (wave & 1) * 64;
    const int fr = lane & 15, fk = (lane >> 4) * 8;

    f32x4 acc[4][4] = {};
    for (int kc = 0; kc < 1024; kc += 32) {
        gload16(A + arow0 + kc + kp0, &sA[chunk0 * 8]);
        gload16(A + arow1 + kc + kp1, &sA[chunk1 * 8]);
        gload16(Bt + brow0 + kc + kp0, &sB[chunk0 * 8]);
        gload16(Bt + brow1 + kc + kp1, &sB[chunk1 * 8]);
        __syncthreads();
        bf16x8 af[4], bfr[4];
#pragma unroll
        for (int i = 0; i < 4; ++i)
            af[i] = *(const bf16x8*)&sA[(wr + i * 16 + fr) * 32 + fk];
#pragma unroll
        for (int j = 0; j < 4; ++j)
            bfr[j] = *(const bf16x8*)&sB[(wc + j * 16 + fr) * 32 + fk];
#pragma unroll
        for (int i = 0; i < 4; ++i)
#pragma unroll
            for (int j = 0; j < 4; ++j)
                acc[i][j] = __builtin_amdgcn_mfma_f32_16x16x32_bf16(
                    af[i], bfr[j], acc[i][j], 0, 0, 0);
        __syncthreads();
    }
    float bv[4];
    int un[4], gn[4];
#pragma unroll
    for (int j = 0; j < 4; ++j) {
        int n = n0 + wc + j * 16 + fr;
        bv[j] = bias[n];
        un[j] = n & 511; gn[j] = n >> 9;
    }
#pragma unroll
    for (int i = 0; i < 4; ++i) {
        int mb = m0 + wr + i * 16 + (lane >> 4) * 4;
#pragma unroll
        for (int j = 0; j < 4; ++j) {
#pragma unroll
            for (int r = 0; r < 4; ++r)
                Zb[(size_t)(mb + r) * 2048 + un[j] * 4 + gn[j]] =
                    f2bf(acc[i][j][r] + bv[j]);
        }
    }
}

// ---------------------------------------------------------------- recurrence
// 32 wgs: dir = bx>>4, slice wgs = bx&15 owns u0 = wgs*32 (x4 gates).
// U bf16 fragments in registers; h exchanged via agent-scope RELAXED atomic
// u32s; barrier B's implicit vmcnt(0) orders h stores before the flag.
// Packed 64B flag line per dir; every wave polls (lanes<16), no post-poll
// barrier; hseq stores fly under poll+gather.
__global__ __launch_bounds__(512, 1) void lstm_chunk(
    const u16* __restrict__ zf, const u16* __restrict__ zb,
    const u16* __restrict__ upk,          // layer base [2 dirs][1048576]
    const int* __restrict__ xmask,
    u32* __restrict__ hbuf32,             // [2 dir][2 parity][8192] u32
    float* __restrict__ cst, float* __restrict__ hst,  // [2*16384]
    u32* __restrict__ flags,              // [2][16] packed (one line/dir)
    u16* __restrict__ hseq,               // [B][T][1024] bf16
    int t0f, int t0b, int C, int sbase) {
    const int bx = blockIdx.x, dir = bx >> 4, wgs = bx & 15, u0 = wgs * 32;
    const u16* z = dir ? zb : zf;         // [B*C][2048] u16, idx u*4+g
    const u16* up = upk + dir * 1048576;
    u32* hb32 = hbuf32 + dir * 16384;
    u32* myflag = flags + dir * 16 + wgs;
    const u32* fbase = flags + dir * 16;
    const int tid = threadIdx.x;
    const int wave = tid >> 6, lane = tid & 63;
    const int cp = wave & 3, bt = wave >> 2, fr = lane & 15, fq = lane >> 4;
    const int row = bt * 16 + fr;                 // batch index for A frags
    const int swz = (row & 7) << 4;

    __shared__ __align__(16) u16 sh[16384];       // 32KB staged h (swizzled)
    __shared__ float sacc[32 * 132];              // gate preacts

    // U fragments -> registers (stationary across the chunk)
    bf16x8 uf0[16], uf1[16];
#pragma unroll
    for (int ks = 0; ks < 16; ++ks) {
        size_t base0 = (((size_t)(wgs * 4 + cp) * 2) * 16 + ks) * 512 + lane * 8;
        uf0[ks] = *(const bf16x8*)(up + base0);
        uf1[ks] = *(const bf16x8*)(up + base0 + 16 * 512);
    }

    const int b0p = tid >> 5, ul = tid & 31, b1p = b0p + 16, ug = u0 + ul;
    const int sidx = (dir * 16 + wgs) * 1024 + tid * 2;
    float c0r = cst[sidx], c1r = cst[sidx + 1];
    float h0r = hst[sidx], h1r = hst[sidx + 1];
    const size_t hs0 = (size_t)b0p * T_ * 1024 + dir * 512 + ug;
    const size_t hs1 = (size_t)b1p * T_ * 1024 + dir * 512 + ug;

    // prologue: stage parity-0 h into LDS (agent atomic loads + swizzled write)
    {
        u32 tmp[16];
#pragma unroll
        for (int k = 0; k < 16; ++k)
            tmp[k] = __hip_atomic_load(hb32 + k * 512 + tid, __ATOMIC_RELAXED,
                                       __HIP_MEMORY_SCOPE_AGENT);
#pragma unroll
        for (int k = 0; k < 16; ++k) {
            int idx = k * 512 + tid;
            int sb = (idx * 4) ^ (((idx >> 8) & 7) << 4);
            *(u32*)((char*)sh + sb) = tmp[k];
        }
    }
    // z/mask for step 0
    ushort4 za0, za1; int mc0, mc1;
    {
        int tc = dir ? (C - 1) : 0;
        int t = dir ? (t0b + C - 1) : t0f;
        za0 = *(const ushort4*)(z + ((size_t)(b0p * C + tc)) * 2048 + ug * 4);
        za1 = *(const ushort4*)(z + ((size_t)(b1p * C + tc)) * 2048 + ug * 4);
        mc0 = xmask[b0p * T_ + t]; mc1 = xmask[b1p * T_ + t];
    }
    __syncthreads();

    u16 hb0s = 0, hb1s = 0;
    for (int st = 0; st < C; ++st) {
        const int t = dir ? (t0b + C - 1 - st) : (t0f + st);
        u32* nx32 = hb32 + (((st & 1) ^ 1) ? 8192 : 0);

        // MFMA from LDS (swizzled) x register U, over K=512
        f32x4 acc0 = {0, 0, 0, 0}, acc1 = {0, 0, 0, 0};
#pragma unroll
        for (int ks = 0; ks < 16; ++ks) {
            int abyte = (row * 1024 + ks * 64 + fq * 16) ^ swz;
            bf16x8 a = *(const bf16x8*)((const char*)sh + abyte);
            acc0 = __builtin_amdgcn_mfma_f32_16x16x32_bf16(a, uf0[ks], acc0, 0, 0, 0);
            acc1 = __builtin_amdgcn_mfma_f32_16x16x32_bf16(a, uf1[ks], acc1, 0, 0, 0);
        }
#pragma unroll
        for (int j = 0; j < 4; ++j) {
            int b = bt * 16 + fq * 4 + j;
            sacc[b * 132 + cp * 32 + fr] = acc0[j];
            sacc[b * 132 + cp * 32 + 16 + fr] = acc1[j];
        }
        __syncthreads();                               // A: sacc visible
        // pointwise gates + state update + coherent h stores
        {
            const float* s0 = sacc + b0p * 132;
            const float* s1 = sacc + b1p * 132;
            float i0 = fsig(bf2f(za0.x) + s0[ul]);
            float f0 = fsig(bf2f(za0.y) + s0[32 + ul]);
            float g0 = ftanh(bf2f(za0.z) + s0[64 + ul]);
            float o0 = fsig(bf2f(za0.w) + s0[96 + ul]);
            if (mc0 != 1) { c0r = f0 * c0r + i0 * g0; h0r = o0 * ftanh(c0r); }
            float i1 = fsig(bf2f(za1.x) + s1[ul]);
            float f1 = fsig(bf2f(za1.y) + s1[32 + ul]);
            float g1 = ftanh(bf2f(za1.z) + s1[64 + ul]);
            float o1 = fsig(bf2f(za1.w) + s1[96 + ul]);
            if (mc1 != 1) { c1r = f1 * c1r + i1 * g1; h1r = o1 * ftanh(c1r); }
            hb0s = f2bf(h0r); hb1s = f2bf(h1r);
            u32 nb0 = __shfl_xor((u32)hb0s, 1, 64);
            u32 nb1 = __shfl_xor((u32)hb1s, 1, 64);
            if ((ul & 1) == 0) {
                u32 pk0 = (u32)hb0s | (nb0 << 16);
                u32 pk1 = (u32)hb1s | (nb1 << 16);
                __hip_atomic_store(nx32 + b0p * 256 + (ug >> 1), pk0,
                                   __ATOMIC_RELAXED, __HIP_MEMORY_SCOPE_AGENT);
                __hip_atomic_store(nx32 + b1p * 256 + (ug >> 1), pk1,
                                   __ATOMIC_RELAXED, __HIP_MEMORY_SCOPE_AGENT);
            }
        }
        __syncthreads();   // B: implicit vmcnt(0) drains every thread's stores
        const u32 tgt = (u32)(sbase + st + 1);
        if (tid == 0)
            __hip_atomic_store(myflag, tgt, __ATOMIC_RELAXED,
                               __HIP_MEMORY_SCOPE_AGENT);
        // hseq stores: fire-and-forget, hidden under poll+gather+stage
        hseq[hs0 + (size_t)t * 1024] = hb0s;
        hseq[hs1 + (size_t)t * 1024] = hb1s;
        // prefetch next-step z/mask (flies during the poll)
        ushort4 zn0, zn1; int mn0, mn1;
        {
            int stn = (st + 1 < C) ? st + 1 : st;
            int tcn = dir ? (C - 1 - stn) : stn;
            int tn = dir ? (t0b + tcn) : (t0f + tcn);
            zn0 = *(const ushort4*)(z + ((size_t)(b0p * C + tcn)) * 2048 + ug * 4);
            zn1 = *(const ushort4*)(z + ((size_t)(b1p * C + tcn)) * 2048 + ug * 4);
            mn0 = xmask[b0p * T_ + tn]; mn1 = xmask[b1p * T_ + tn];
        }
        // per-wave poll of the packed flag line (lanes<16 issue loads)
        {
            u32 v = 0xffffffffu;
            if (lane < 16)
                v = __hip_atomic_load(fbase + lane, __ATOMIC_RELAXED,
                                      __HIP_MEMORY_SCOPE_AGENT);
            while (!__all(v >= tgt)) {
                if (lane < 16)
                    v = __hip_atomic_load(fbase + lane, __ATOMIC_RELAXED,
                                          __HIP_MEMORY_SCOPE_AGENT);
            }
        }
        // stage next-parity h into LDS (coalesced agent loads, swizzled write)
        if (st + 1 < C) {
            const u32* src = hb32 + (((st + 1) & 1) ? 8192 : 0);
            u32 tmp[16];
#pragma unroll
            for (int k = 0; k < 16; ++k)
                tmp[k] = __hip_atomic_load(src + k * 512 + tid, __ATOMIC_RELAXED,
                                           __HIP_MEMORY_SCOPE_AGENT);
#pragma unroll
            for (int k = 0; k < 16; ++k) {
                int idx = k * 512 + tid;
                int sb = (idx * 4) ^ (((idx >> 8) & 7) << 4);
                *(u32*)((char*)sh + sb) = tmp[k];
            }
        }
        za0 = zn0; za1 = zn1; mc0 = mn0; mc1 = mn1;
        __syncthreads();                               // C: sh staged by all
    }
    cst[sidx] = c0r; cst[sidx + 1] = c1r;
    hst[sidx] = h0r; hst[sidx + 1] = h1r;
}

// ---------------------------------------------------------------- heads
__global__ __launch_bounds__(256) void heads_kernel(
    const u16* __restrict__ xin,
    const float* __restrict__ Wp, const float* __restrict__ bp,
    const float* __restrict__ Wbu, const float* __restrict__ bbu,
    const float* __restrict__ Wss3, const float* __restrict__ bss3,
    const float* __restrict__ Wss8, const float* __restrict__ bss8,
    float* __restrict__ out) {
    const int r = blockIdx.x * 4 + (threadIdx.x >> 6);
    const int lane = threadIdx.x & 63;
    const u16* xr = xin + (size_t)r * 1024 + lane * 16;
    uint4 q0 = *(const uint4*)xr;
    uint4 q1 = *(const uint4*)(xr + 8);
    float xv[16];
    u32 qs[8] = { q0.x, q0.y, q0.z, q0.w, q1.x, q1.y, q1.z, q1.w };
#pragma unroll
    for (int i = 0; i < 8; ++i) {
        xv[i * 2]     = fmaxf(__uint_as_float((qs[i] & 0xffffu) << 16), 0.0f);
        xv[i * 2 + 1] = fmaxf(__uint_as_float(qs[i] & 0xffff0000u), 0.0f);
    }
    float acc[15] = {};
    const int k0 = lane * 16;
#pragma unroll
    for (int kk = 0; kk < 16; kk++) {
        float xk = xv[kk];
        int k = k0 + kk;
        acc[0] += xk * Wp[k * 2];      acc[1] += xk * Wp[k * 2 + 1];
        acc[2] += xk * Wbu[k * 2];     acc[3] += xk * Wbu[k * 2 + 1];
        acc[4] += xk * Wss3[k * 3];    acc[5] += xk * Wss3[k * 3 + 1];
        acc[6] += xk * Wss3[k * 3 + 2];
#pragma unroll
        for (int o = 0; o < 8; o++) acc[7 + o] += xk * Wss8[k * 8 + o];
    }
#pragma unroll
    for (int o = 0; o < 15; o++) {
#pragma unroll
        for (int off = 32; off; off >>= 1) acc[o] += __shfl_xor(acc[o], off, 64);
    }
    if (lane == 0) {
        float a0 = acc[0] + bp[0], a1 = acc[1] + bp[1];
        float mx = fmaxf(a0, a1);
        float e0 = expf(a0 - mx), e1 = expf(a1 - mx);
        float ssum = e0 + e1;
        out[(size_t)r * 2] = e0 / ssum;
        out[(size_t)r * 2 + 1] = e1 / ssum;
        float* ob = out + 65536;
        ob[r * 2] = acc[2] + bbu[0]; ob[r * 2 + 1] = acc[3] + bbu[1];
        float* o3 = out + 131072;
        o3[r * 3 + 0] = acc[4] + bss3[0];
        o3[r * 3 + 1] = acc[5] + bss3[1];
        o3[r * 3 + 2] = acc[6] + bss3[2];
        float* o8 = out + 229376;
#pragma unroll
        for (int o = 0; o < 8; o++) o8[r * 8 + o] = acc[7 + o] + bss8[o];
    }
}

// ---------------------------------------------------------------- launch
extern "C" void kernel_launch(void* const* d_in, const int* in_sizes, int n_in,
                              void* d_out, int out_size, void* d_ws, size_t ws_size,
                              hipStream_t stream) {
    const float* x = (const float*)d_in[0];
    const int* xmask = (const int*)d_in[1];
    const float* Wf = (const float*)d_in[2];
    const float* Uf = (const float*)d_in[3];
    const float* bfp = (const float*)d_in[4];
    const float* Wb = (const float*)d_in[5];
    const float* Ub = (const float*)d_in[6];
    const float* bbp = (const float*)d_in[7];
    const float* Wp = (const float*)d_in[8];
    const float* bp = (const float*)d_in[9];
    const float* Wbu = (const float*)d_in[10];
    const float* bbu = (const float*)d_in[11];
    const float* Wss3 = (const float*)d_in[12];
    const float* bss3 = (const float*)d_in[13];
    const float* Wss8 = (const float*)d_in[14];
    const float* bss8 = (const float*)d_in[15];

    char* wsb = (char*)d_ws;
    u16* actA = (u16*)wsb;                               // 64 MB
    u16* actB = (u16*)(wsb + (64ull << 20));             // 64 MB
    u16* wt   = (u16*)(wsb + (128ull << 20));            // 24 MB
    u16* upk  = (u16*)(wsb + (152ull << 20));            // 12 MB
    char* stb = wsb + (164ull << 20);                    // states
    u32* hbuf32 = (u32*)stb;                             // 131072 B
    float* cst = (float*)(stb + 131072);                 // 131072 B
    float* hst = (float*)(stb + 262144);                 // 131072 B
    u32* flags = (u32*)(stb + 393216);                   // 128 B packed
    const int stateFloats = (393216 + 128) / 4;

    size_t fixedB = 165ull << 20;
    int C = 1024;
    while (C > 128 && fixedB + 262144ull * C > ws_size) C >>= 1;
    int lgC = 31 - __builtin_clz((unsigned)C);
    u16* zf = (u16*)(wsb + fixedB);
    u16* zb = zf + (size_t)B_ * C * 2048;

    conv_bf16<<<dim3(8388608 / 256), 256, 0, stream>>>(x, actA);
    transpose_w<<<dim3(32, 16, 6), 256, 0, stream>>>(Wf, Wb, wt);
    pack_u<<<dim3(512, 6), 256, 0, stream>>>(Uf, Ub, upk);

    const u16* cur = actA;
    for (int l = 0; l < 3; l++) {
        u16* dst = (l & 1) ? actA : actB;
        zero_mem<<<dim3((stateFloats + 255) / 256), 256, 0, stream>>>(
            (float*)stb, stateFloats);
        u16* wtf = wt + (size_t)(l * 2 + 0) * NG * 1024;
        u16* wtb = wt + (size_t)(l * 2 + 1) * NG * 1024;
        const u16* upkl = upk + (size_t)l * 2 * 1048576;
        const float* bfl = bfp + l * NG;
        const float* bbl = bbp + l * NG;
        for (int c0 = 0; c0 < T_; c0 += C) {
            int t0f = c0;
            int t0b = T_ - c0 - C;
            dim3 ggrid(NG / 128, (B_ * C) / 128);
            gemm_mfma<<<ggrid, 256, 0, stream>>>(cur, wtf, bfl, zf, t0f, lgC);
            gemm_mfma<<<ggrid, 256, 0, stream>>>(cur, wtb, bbl, zb, t0b, lgC);

            const u16* a_zf = zf; const u16* a_zb = zb;
            const u16* a_up = upkl; const int* a_xm = xmask;
            u32* a_hb = hbuf32; float* a_cs = cst; float* a_hs = hst;
            u32* a_fl = flags; u16* a_hseq = dst;
            int a_t0f = t0f, a_t0b = t0b, a_C = C, a_sb = c0;
            void* kargs[] = { &a_zf, &a_zb, &a_up, &a_xm, &a_hb, &a_cs, &a_hs,
                              &a_fl, &a_hseq, &a_t0f, &a_t0b, &a_C, &a_sb };
            hipLaunchCooperativeKernel((void*)lstm_chunk, dim3(32), dim3(512),
                                       kargs, 0, stream);
        }
        cur = dst;
    }
    heads_kernel<<<dim3(B_ * T_ / 4), 256, 0, stream>>>(
        cur, Wp, bp, Wbu, bbu, Wss3, bss3, Wss8, bss8, (float*)d_out);
}